// Round 3
// baseline (2151.799 us; speedup 1.0000x reference)
//
#include <hip/hip_runtime.h>
#include <math.h>
#include <float.h>

#define NB    65536
#define DIN   1408
#define PDIM  256
#define KCB   64
#define TAU   3e-4f   // bf16x3 GEMM dist error ~3e-5 -> 7x margin; fp64 refine covers flags
#define NKB   44      // DIN/32 K-tiles

// ---------------- workspace layout ----------------
// [0]       int    cnt (ambiguous-row counter; zeroed via memsetAsync)
// [64]      int    cand[NB]
// [262208]  int    list[NB]
// [524352]  double partials[NB/64]      (1024 * 8 B)
// [1048832] float  g[NB*PDIM]
// WT_hi/WT_lo (bf16 W, tile-major pre-swizzled) live in the HEAD OF d_out:
// out is fully rewritten by K3/K4 afterwards, so it is legal scratch for K2.
#define OFF_CNT   0
#define OFF_CAND  64
#define OFF_LIST  262208
#define OFF_PART  524352
#define OFF_G     1048832
#define WT_US     360448        // ushorts per WT array (44*16KB/2)
#define WTL_OFS   368640        // ushort offset of WT_lo within out (16B aligned)

typedef short bf16x8 __attribute__((ext_vector_type(8)));
typedef unsigned short us8 __attribute__((ext_vector_type(8)));
typedef float f32x4  __attribute__((ext_vector_type(4)));

static __device__ __forceinline__ float wave_sum(float v) {
#pragma unroll
  for (int m = 32; m; m >>= 1) v += __shfl_xor(v, m, 64);
  return v;
}

static __device__ __forceinline__ void gl_lds16(const void* gsrc, void* ldst) {
  __builtin_amdgcn_global_load_lds(
      (const __attribute__((address_space(1))) unsigned int*)gsrc,
      (__attribute__((address_space(3))) unsigned int*)ldst, 16, 0, 0);
}

// K1w: convert W (fp32 [k][col]) -> bf16 hi/lo, tile-major layout matching K2's
// LDS image exactly: chunk(kb) is [col][quad qp][8 us] with qp = q ^ ((col>>1)&3).
// K2 then streams it linearly via global_load_lds; swizzle applied on ds_read only.
__global__ __launch_bounds__(256) void k1_wconv(const float* __restrict__ W,
                                                unsigned short* __restrict__ WTh,
                                                unsigned short* __restrict__ WTl) {
  const int gg = blockIdx.x * 256 + threadIdx.x;   // chunk id, 45056 total
  const int kb = gg >> 10;
  const int rem = gg & 1023;
  const int col = rem >> 2;
  const int qp = rem & 3;
  const int q = qp ^ ((col >> 1) & 3);
  const int kbase = kb * 32 + q * 8;
  us8 h8, l8;
#pragma unroll
  for (int j = 0; j < 8; ++j) {
    float v = W[(size_t)(kbase + j) * PDIM + col];
    unsigned u = __float_as_uint(v);
    float hif = __uint_as_float(u & 0xffff0000u);
    h8[j] = (unsigned short)(u >> 16);
    l8[j] = (unsigned short)((__float_as_uint(v - hif) + 0x8000u) >> 16);
  }
  *(us8*)(WTh + ((size_t)gg << 3)) = h8;
  *(us8*)(WTl + ((size_t)gg << 3)) = l8;
}

// K2: g = (A @ W) * inv_row_norm via bf16x3 MFMA split GEMM.
// block = 128 rows x 256 cols, 512 threads = 8 waves (2M x 4N), 64x64/wave.
// W: global_load_lds from pre-swizzled WT (no VALU, no VGPR). A: reg->split->
// swizzled ds_write_b128. Unpadded 64B LDS rows + quad-XOR swizzle -> conflict-free.
__global__ __launch_bounds__(512, 6) void k2_gemm(const float* __restrict__ A,
                                                  const unsigned short* __restrict__ WTh,
                                                  const unsigned short* __restrict__ WTl,
                                                  float* __restrict__ g) {
  __shared__ unsigned short As_hi[128][32], As_lo[128][32];
  __shared__ unsigned short Ws_hi[PDIM][32], Ws_lo[PDIM][32];
  __shared__ float rn[128];
  const int t = threadIdx.x;
  const int lane = t & 63;
  const int w = t >> 6;
  const int wm = w >> 2, wn = w & 3;
  const int row0 = blockIdx.x * 128;
  // A staging: thread covers row ar, logical quad aq (k = aq*8..aq*8+7)
  const int ar = t >> 2, aq = t & 3;
  const int sa = (ar >> 1) & 3;
  const int awoff = ar * 64 + ((aq ^ sa) << 4);
  const float* Ap = A + (size_t)(row0 + ar) * DIN + (aq << 3);
  // W staging src/dst (per-lane src, wave-uniform dst base)
  const unsigned short* wsrc0 =
      WTh + (size_t)((w << 4) + (lane >> 2)) * 32 + ((lane & 3) << 3);
  const unsigned short* wsrc0l =
      WTl + (size_t)((w << 4) + (lane >> 2)) * 32 + ((lane & 3) << 3);
  char* wdstH = (char*)Ws_hi + (w << 10);
  char* wdstL = (char*)Ws_lo + (w << 10);

  const f32x4 zero = {0.f, 0.f, 0.f, 0.f};
  f32x4 acc[4][4];
#pragma unroll
  for (int i = 0; i < 4; ++i)
#pragma unroll
    for (int j = 0; j < 4; ++j) acc[i][j] = zero;

  // fragment read addressing (swizzle s depends only on fr since bases are mult-16)
  const int fr = lane & 15, qd = lane >> 4;
  const int qsw = ((qd ^ ((fr >> 1) & 3)) << 4);

  // prologue: A tile 0 into regs
  float4 a0 = *(const float4*)(Ap);
  float4 a1 = *(const float4*)(Ap + 4);

  float ss = 0.f;
  for (int kb = 0; kb < NKB; ++kb) {
    // ---- issue W tile loads (direct to LDS, pre-swizzled file) ----
    {
      const unsigned short* sh = wsrc0 + ((size_t)kb << 13);
      const unsigned short* sl = wsrc0l + ((size_t)kb << 13);
      gl_lds16(sh, wdstH);
      gl_lds16(sh + 4096, wdstH + 8192);
      gl_lds16(sl, wdstL);
      gl_lds16(sl + 4096, wdstL + 8192);
    }
    // ---- A: row sumsq + split -> swizzled LDS ----
    ss += a0.x * a0.x + a0.y * a0.y + a0.z * a0.z + a0.w * a0.w
        + a1.x * a1.x + a1.y * a1.y + a1.z * a1.z + a1.w * a1.w;
    {
      us8 h8, l8;
      float av[8] = {a0.x, a0.y, a0.z, a0.w, a1.x, a1.y, a1.z, a1.w};
#pragma unroll
      for (int j = 0; j < 8; ++j) {
        unsigned u = __float_as_uint(av[j]);
        float hif = __uint_as_float(u & 0xffff0000u);
        h8[j] = (unsigned short)(u >> 16);
        l8[j] = (unsigned short)((__float_as_uint(av[j] - hif) + 0x8000u) >> 16);
      }
      *(us8*)((char*)As_hi + awoff) = h8;
      *(us8*)((char*)As_lo + awoff) = l8;
    }
    __syncthreads();   // W in LDS (vmcnt drain), A writes visible

    // ---- prefetch next A tile into regs (drains at end barrier) ----
    const int kn = (kb + 1 < NKB) ? (kb + 1) << 5 : 0;
    float4 na0 = *(const float4*)(Ap + kn);
    float4 na1 = *(const float4*)(Ap + kn + 4);

    // ---- fragments + 3-product MFMA ----
    {
      bf16x8 ah[4], al[4], bh[4], bl[4];
#pragma unroll
      for (int mf = 0; mf < 4; ++mf) {
        const int off = ((wm << 6) + (mf << 4) + fr) * 64 + qsw;
        ah[mf] = *(const bf16x8*)((const char*)As_hi + off);
        al[mf] = *(const bf16x8*)((const char*)As_lo + off);
      }
#pragma unroll
      for (int nf = 0; nf < 4; ++nf) {
        const int off = ((wn << 6) + (nf << 4) + fr) * 64 + qsw;
        bh[nf] = *(const bf16x8*)((const char*)Ws_hi + off);
        bl[nf] = *(const bf16x8*)((const char*)Ws_lo + off);
      }
#pragma unroll
      for (int mf = 0; mf < 4; ++mf)
#pragma unroll
        for (int nf = 0; nf < 4; ++nf) {
          acc[mf][nf] = __builtin_amdgcn_mfma_f32_16x16x32_bf16(ah[mf], bh[nf], acc[mf][nf], 0, 0, 0);
          acc[mf][nf] = __builtin_amdgcn_mfma_f32_16x16x32_bf16(al[mf], bh[nf], acc[mf][nf], 0, 0, 0);
          acc[mf][nf] = __builtin_amdgcn_mfma_f32_16x16x32_bf16(ah[mf], bl[nf], acc[mf][nf], 0, 0, 0);
        }
    }
    __syncthreads();
    a0 = na0; a1 = na1;
  }

  // reduce the 4 staging partials per row (threads 4r..4r+3 are wave-adjacent)
  ss += __shfl_xor(ss, 1, 64);
  ss += __shfl_xor(ss, 2, 64);
  if ((t & 3) == 0) rn[ar] = ss;
  __syncthreads();
  if (t < 128) rn[t] = 1.0f / fmaxf(sqrtf(rn[t]), 1e-12f);
  __syncthreads();

  // C/D layout: col = lane&15, row = (lane>>4)*4 + reg  [m89-verified]
  const int er = lane & 15, eq = (lane >> 4) << 2;
#pragma unroll
  for (int mf = 0; mf < 4; ++mf) {
#pragma unroll
    for (int nf = 0; nf < 4; ++nf) {
#pragma unroll
      for (int r = 0; r < 4; ++r) {
        const int row = (wm << 6) + (mf << 4) + eq + r;
        const int col = (wn << 6) + (nf << 4) + er;
        g[(size_t)(row0 + row) * PDIM + col] = acc[mf][nf][r] * rn[row];
      }
    }
  }
}

// K3: 256 threads / 4 waves per block, 64 rows per block. (unchanged)
#define RB 64
#define CPAD 260
__global__ __launch_bounds__(256, 1) void k3_epilogue(const float* __restrict__ g,
                                                      const float* __restrict__ bvec,
                                                      const float* __restrict__ gamma,
                                                      const float* __restrict__ beta,
                                                      const float* __restrict__ C,
                                                      float* __restrict__ out,
                                                      int* __restrict__ cand,
                                                      int* __restrict__ list,
                                                      int* __restrict__ cnt,
                                                      double* __restrict__ partials) {
  __shared__ float Cs[KCB][CPAD];
  __shared__ float zsh[RB][CPAD];
  __shared__ float ccs[KCB];
  __shared__ float zzs[RB];
  __shared__ float lb[RB];
  __shared__ int idxsh[RB];
  const int t = threadIdx.x;
  const int lane = t & 63, w = t >> 6;
  const int row0 = blockIdx.x * RB;

  float4 creg[16];
#pragma unroll
  for (int i = 0; i < 16; ++i)
    creg[i] = *(const float4*)(C + (size_t)((t + (i << 8)) << 2));
#pragma unroll
  for (int i = 0; i < 16; ++i) {
    const int idx = t + (i << 8);
    *(float4*)&Cs[idx >> 6][(idx & 63) << 2] = creg[i];
  }
  __syncthreads();

  {
    const int kr = t >> 2, q = t & 3;
    float s = 0.f;
#pragma unroll
    for (int c = 0; c < 16; ++c) {
      float4 v = *(const float4*)&Cs[kr][(q << 6) + (c << 2)];
      s += v.x * v.x + v.y * v.y + v.z * v.z + v.w * v.w;
    }
    s += __shfl_xor(s, 1, 64);
    s += __shfl_xor(s, 2, 64);
    if (q == 0) ccs[kr] = s;
  }

  float4 bv = *(const float4*)(bvec + (lane << 2));
  float4 gm = *(const float4*)(gamma + (lane << 2));
  float4 bt = *(const float4*)(beta + (lane << 2));
  float4 gvv[16];
#pragma unroll
  for (int rr = 0; rr < 16; ++rr)
    gvv[rr] = *(const float4*)(g + (size_t)(row0 + (w << 4) + rr) * PDIM + (lane << 2));
#pragma unroll
  for (int rr = 0; rr < 16; ++rr) {
    const int r = (w << 4) + rr;
    float h0 = gvv[rr].x + bv.x, h1 = gvv[rr].y + bv.y;
    float h2 = gvv[rr].z + bv.z, h3 = gvv[rr].w + bv.w;
    float mu = wave_sum(h0 + h1 + h2 + h3) * (1.0f / 256.0f);
    float d0 = h0 - mu, d1 = h1 - mu, d2 = h2 - mu, d3 = h3 - mu;
    float var = wave_sum(d0 * d0 + d1 * d1 + d2 * d2 + d3 * d3) * (1.0f / 256.0f);
    float invs = 1.0f / sqrtf(var + 1e-5f);
    float zp0 = d0 * invs * gm.x + bt.x, zp1 = d1 * invs * gm.y + bt.y;
    float zp2 = d2 * invs * gm.z + bt.z, zp3 = d3 * invs * gm.w + bt.w;
    float nz = wave_sum(zp0 * zp0 + zp1 * zp1 + zp2 * zp2 + zp3 * zp3);
    float zn = 1.0f / fmaxf(sqrtf(nz), 1e-12f);
    float z0 = zp0 * zn, z1 = zp1 * zn, z2 = zp2 * zn, z3 = zp3 * zn;
    float zz = wave_sum(z0 * z0 + z1 * z1 + z2 * z2 + z3 * z3);
    float4 zf = {z0, z1, z2, z3};
    *(float4*)&zsh[r][lane << 2] = zf;
    if (lane == 0) zzs[r] = zz;
  }
  __syncthreads();

  const int kg = t & 15, rg = t >> 4;
  float p[4][4];
#pragma unroll
  for (int i = 0; i < 4; ++i)
#pragma unroll
    for (int j = 0; j < 4; ++j) p[i][j] = 0.f;

#pragma unroll 2
  for (int c4 = 0; c4 < 64; ++c4) {
    const int co = c4 << 2;
    float4 cv[4], zv[4];
#pragma unroll
    for (int ki = 0; ki < 4; ++ki) cv[ki] = *(const float4*)&Cs[kg + (ki << 4)][co];
#pragma unroll
    for (int ri = 0; ri < 4; ++ri) zv[ri] = *(const float4*)&zsh[rg + (ri << 4)][co];
#pragma unroll
    for (int ki = 0; ki < 4; ++ki)
#pragma unroll
      for (int ri = 0; ri < 4; ++ri) {
        p[ki][ri] = fmaf(cv[ki].x, zv[ri].x, p[ki][ri]);
        p[ki][ri] = fmaf(cv[ki].y, zv[ri].y, p[ki][ri]);
        p[ki][ri] = fmaf(cv[ki].z, zv[ri].z, p[ki][ri]);
        p[ki][ri] = fmaf(cv[ki].w, zv[ri].w, p[ki][ri]);
      }
  }

  float ccl[4];
#pragma unroll
  for (int ki = 0; ki < 4; ++ki) ccl[ki] = ccs[kg + (ki << 4)];

  float b1[4], b2[4];
  int i1[4];
#pragma unroll
  for (int ri = 0; ri < 4; ++ri) {
    const float zz = zzs[rg + (ri << 4)];
    b1[ri] = zz - 2.0f * p[0][ri] + ccl[0];
    i1[ri] = kg;
    b2[ri] = FLT_MAX;
#pragma unroll
    for (int ki = 1; ki < 4; ++ki) {
      const float d = zz - 2.0f * p[ki][ri] + ccl[ki];
      if (d < b1[ri]) { b2[ri] = b1[ri]; b1[ri] = d; i1[ri] = kg + (ki << 4); }
      else b2[ri] = fminf(b2[ri], d);
    }
  }
#pragma unroll
  for (int m = 1; m < 16; m <<= 1) {
#pragma unroll
    for (int ri = 0; ri < 4; ++ri) {
      float ob1 = __shfl_xor(b1[ri], m, 64);
      int oi1 = __shfl_xor(i1[ri], m, 64);
      float ob2 = __shfl_xor(b2[ri], m, 64);
      if (ob1 < b1[ri] || (ob1 == b1[ri] && oi1 < i1[ri])) {
        b2[ri] = fminf(b1[ri], ob2);
        b1[ri] = ob1; i1[ri] = oi1;
      } else {
        b2[ri] = fminf(b2[ri], ob1);
      }
    }
  }
  if (kg == 0) {
#pragma unroll
    for (int ri = 0; ri < 4; ++ri) {
      const int r = rg + (ri << 4);
      const int grow = row0 + r;
      cand[grow] = i1[ri];
      out[(size_t)NB * PDIM + grow] = (float)i1[ri];
      idxsh[r] = i1[ri];
      lb[r] = b1[ri];
      if (b2[ri] - b1[ri] < TAU) {
        int wpos = atomicAdd(cnt, 1);
        list[wpos] = grow;
      }
    }
  }
  __syncthreads();

#pragma unroll 4
  for (int rr = 0; rr < 16; ++rr) {
    const int r = (w << 4) + rr;
    const int ii = idxsh[r];
    float4 cv = *(const float4*)&Cs[ii][lane << 2];
    *(float4*)(out + (size_t)(row0 + r) * PDIM + (lane << 2)) = cv;
  }
  if (t == 0) {
    double s = 0.0;
    for (int r = 0; r < RB; ++r) s += (double)lb[r];
    partials[blockIdx.x] = s;
  }
}

// K4: fp64 recompute of flagged rows; fix index, output row, loss partial.
__global__ __launch_bounds__(256) void k4_refine(const float* __restrict__ A,
                                                 const float* __restrict__ W,
                                                 const float* __restrict__ bvec,
                                                 const float* __restrict__ gamma,
                                                 const float* __restrict__ beta,
                                                 const float* __restrict__ C,
                                                 const int* __restrict__ list,
                                                 const int* __restrict__ cnt,
                                                 int* __restrict__ cand,
                                                 float* __restrict__ out,
                                                 double* __restrict__ partials) {
  __shared__ double xs[DIN];
  __shared__ double red[256];
  __shared__ double zd[PDIM];
  __shared__ int idx2[2];
  const int t = threadIdx.x;
  const int n = *cnt;
  for (int it = blockIdx.x; it < n; it += gridDim.x) {
    const int row = list[it];
    __syncthreads();
    for (int i = t; i < DIN; i += 256) xs[i] = (double)A[(size_t)row * DIN + i];
    __syncthreads();
    double s = 0.0;
    for (int i = t; i < DIN; i += 256) s += xs[i] * xs[i];
    red[t] = s; __syncthreads();
    for (int m = 128; m; m >>= 1) { if (t < m) red[t] += red[t + m]; __syncthreads(); }
    const double inv = 1.0 / fmax(sqrt(red[0]), 1e-12);

    double gj = 0.0;
#pragma unroll 8
    for (int k = 0; k < DIN; ++k) gj += xs[k] * (double)W[(size_t)k * PDIM + t];
    const double h = gj * inv + (double)bvec[t];

    __syncthreads(); red[t] = h; __syncthreads();
    for (int m = 128; m; m >>= 1) { if (t < m) red[t] += red[t + m]; __syncthreads(); }
    const double mu = red[0] * (1.0 / 256.0);
    const double d = h - mu;
    __syncthreads(); red[t] = d * d; __syncthreads();
    for (int m = 128; m; m >>= 1) { if (t < m) red[t] += red[t + m]; __syncthreads(); }
    const double invs = 1.0 / sqrt(red[0] * (1.0 / 256.0) + 1e-5);
    const double zp = d * invs * (double)gamma[t] + (double)beta[t];
    __syncthreads(); red[t] = zp * zp; __syncthreads();
    for (int m = 128; m; m >>= 1) { if (t < m) red[t] += red[t + m]; __syncthreads(); }
    const double zn = 1.0 / fmax(sqrt(red[0]), 1e-12);
    const double z = zp * zn;
    zd[t] = z;
    __syncthreads(); red[t] = z * z; __syncthreads();
    for (int m = 128; m; m >>= 1) { if (t < m) red[t] += red[t + m]; __syncthreads(); }
    const double zz = red[0];
    __syncthreads();
    if (t < KCB) {
      double p = 0.0, cc = 0.0;
      for (int c = 0; c < PDIM; ++c) {
        double cv = (double)C[(size_t)t * PDIM + c];
        p += zd[c] * cv; cc += cv * cv;
      }
      red[t] = zz - 2.0 * p + cc;
    }
    __syncthreads();
    if (t == 0) {
      double best = red[0]; int bi = 0;
      for (int k = 1; k < KCB; ++k) if (red[k] < best) { best = red[k]; bi = k; }
      const int old = cand[row];
      idx2[0] = bi; idx2[1] = old;
      if (bi != old) {
        cand[row] = bi;
        out[(size_t)NB * PDIM + row] = (float)bi;
        atomicAdd(&partials[row >> 6], red[bi] - red[old]);
      }
    }
    __syncthreads();
    if (idx2[0] != idx2[1])
      out[(size_t)row * PDIM + t] = C[(size_t)idx2[0] * PDIM + t];
    __syncthreads();
  }
}

// K6: reduce loss partials, write scalar.
__global__ __launch_bounds__(256) void k6_finalize(const double* __restrict__ partials,
                                                   float* __restrict__ out) {
  __shared__ double red[256];
  const int t = threadIdx.x;
  double s = 0.0;
  for (int i = t; i < NB / RB; i += 256) s += partials[i];
  red[t] = s; __syncthreads();
  for (int m = 128; m; m >>= 1) { if (t < m) red[t] += red[t + m]; __syncthreads(); }
  if (t == 0)
    out[(size_t)NB * PDIM + NB] = (float)(0.25 * red[0] / ((double)NB * (double)PDIM));
}

extern "C" void kernel_launch(void* const* d_in, const int* in_sizes, int n_in,
                              void* d_out, int out_size, void* d_ws, size_t ws_size,
                              hipStream_t stream) {
  const float* z_frame  = (const float*)d_in[0];
  const float* W        = (const float*)d_in[1];
  const float* bvec     = (const float*)d_in[2];
  const float* gamma    = (const float*)d_in[3];
  const float* beta     = (const float*)d_in[4];
  const float* codebook = (const float*)d_in[5];
  float* out = (float*)d_out;

  char* ws = (char*)d_ws;
  int*    cnt      = (int*)(ws + OFF_CNT);
  int*    cand     = (int*)(ws + OFF_CAND);
  int*    list     = (int*)(ws + OFF_LIST);
  double* partials = (double*)(ws + OFF_PART);
  float*  g        = (float*)(ws + OFF_G);

  // WT scratch lives in the head of out (fully rewritten by K3/K4 later)
  unsigned short* WTh = (unsigned short*)out;
  unsigned short* WTl = WTh + WTL_OFS;

  hipMemsetAsync(ws + OFF_CNT, 0, 64, stream);

  k1_wconv<<<176, 256, 0, stream>>>(W, WTh, WTl);
  k2_gemm<<<NB / 128, 512, 0, stream>>>(z_frame, WTh, WTl, g);
  k3_epilogue<<<NB / RB, 256, 0, stream>>>(g, bvec, gamma, beta, codebook,
                                           out, cand, list, cnt, partials);
  k4_refine<<<256, 256, 0, stream>>>(z_frame, W, bvec, gamma, beta, codebook,
                                     list, cnt, cand, out, partials);
  k6_finalize<<<1, 256, 0, stream>>>(partials, out);
}

// Round 4
// 876.567 us; speedup vs baseline: 2.4548x; 2.4548x over previous
//
#include <hip/hip_runtime.h>
#include <math.h>
#include <float.h>

#define NB    65536
#define DIN   1408
#define PDIM  256
#define KCB   64
#define TAU   3e-4f   // bf16x3 GEMM dist error ~3e-5 -> 7x margin; fp64 refine covers flags
#define NKB   44      // DIN/32 K-tiles

// ---------------- workspace layout ----------------
// [0]       int    cnt (ambiguous-row counter; zeroed via memsetAsync)
// [64]      int    cand[NB]
// [262208]  int    list[NB]
// [524352]  double partials[NB/64]      (1024 * 8 B)
// [1048832] float  g[NB*PDIM]
// WT_hi/WT_lo (bf16 W, tile-major pre-swizzled) live in the HEAD OF d_out:
// out is fully rewritten by K3/K4 afterwards, so it is legal scratch for K2.
#define OFF_CNT   0
#define OFF_CAND  64
#define OFF_LIST  262208
#define OFF_PART  524352
#define OFF_G     1048832
#define WT_US     360448        // ushorts per WT array (44*16KB/2)
#define WTL_OFS   368640        // ushort offset of WT_lo within out (16B aligned)

typedef short bf16x8 __attribute__((ext_vector_type(8)));
typedef unsigned short us8 __attribute__((ext_vector_type(8)));
typedef float f32x4  __attribute__((ext_vector_type(4)));

static __device__ __forceinline__ float wave_sum(float v) {
#pragma unroll
  for (int m = 32; m; m >>= 1) v += __shfl_xor(v, m, 64);
  return v;
}

static __device__ __forceinline__ void gl_lds16(const void* gsrc, void* ldst) {
  __builtin_amdgcn_global_load_lds(
      (const __attribute__((address_space(1))) unsigned int*)gsrc,
      (__attribute__((address_space(3))) unsigned int*)ldst, 16, 0, 0);
}

// K1w: convert W (fp32 [k][col]) -> bf16 hi/lo, tile-major layout matching K2's
// LDS image exactly: chunk(kb) is [col][quad qp][8 us] with qp = q ^ ((col>>1)&3).
// K2 then streams it linearly via global_load_lds; swizzle applied on ds_read only.
__global__ __launch_bounds__(256) void k1_wconv(const float* __restrict__ W,
                                                unsigned short* __restrict__ WTh,
                                                unsigned short* __restrict__ WTl) {
  const int gg = blockIdx.x * 256 + threadIdx.x;   // chunk id, 45056 total
  const int kb = gg >> 10;
  const int rem = gg & 1023;
  const int col = rem >> 2;
  const int qp = rem & 3;
  const int q = qp ^ ((col >> 1) & 3);
  const int kbase = kb * 32 + q * 8;
  us8 h8, l8;
#pragma unroll
  for (int j = 0; j < 8; ++j) {
    float v = W[(size_t)(kbase + j) * PDIM + col];
    unsigned u = __float_as_uint(v);
    float hif = __uint_as_float(u & 0xffff0000u);
    h8[j] = (unsigned short)(u >> 16);
    l8[j] = (unsigned short)((__float_as_uint(v - hif) + 0x8000u) >> 16);
  }
  *(us8*)(WTh + ((size_t)gg << 3)) = h8;
  *(us8*)(WTl + ((size_t)gg << 3)) = l8;
}

// K2: g = (A @ W) * inv_row_norm via bf16x3 MFMA split GEMM.
// block = 128 rows x 256 cols, 512 threads = 8 waves (2M x 4N), 64x64/wave.
// W: global_load_lds from pre-swizzled WT (no VALU, no VGPR). A: reg->split->
// swizzled ds_write_b128. Unpadded 64B LDS rows + quad-XOR swizzle -> conflict-free.
// NOTE: launch_bounds min-waves MUST stay at 2 — the unified VGPR+AGPR file holds
// ~136 regs/lane (64 AGPR acc + ~72 VGPR); a cap of 85 (w=6) spills acc to
// scratch (R3: 6.3 GB HBM scratch traffic, 5x slowdown).
__global__ __launch_bounds__(512, 2) void k2_gemm(const float* __restrict__ A,
                                                  const unsigned short* __restrict__ WTh,
                                                  const unsigned short* __restrict__ WTl,
                                                  float* __restrict__ g) {
  __shared__ unsigned short As_hi[128][32], As_lo[128][32];
  __shared__ unsigned short Ws_hi[PDIM][32], Ws_lo[PDIM][32];
  __shared__ float rn[128];
  const int t = threadIdx.x;
  const int lane = t & 63;
  const int w = t >> 6;
  const int wm = w >> 2, wn = w & 3;
  const int row0 = blockIdx.x * 128;
  // A staging: thread covers row ar, logical quad aq (k = aq*8..aq*8+7)
  const int ar = t >> 2, aq = t & 3;
  const int sa = (ar >> 1) & 3;
  const int awoff = ar * 64 + ((aq ^ sa) << 4);
  const float* Ap = A + (size_t)(row0 + ar) * DIN + (aq << 3);
  // W staging src/dst (per-lane src, wave-uniform dst base)
  const unsigned short* wsrc0 =
      WTh + (size_t)((w << 4) + (lane >> 2)) * 32 + ((lane & 3) << 3);
  const unsigned short* wsrc0l =
      WTl + (size_t)((w << 4) + (lane >> 2)) * 32 + ((lane & 3) << 3);
  char* wdstH = (char*)Ws_hi + (w << 10);
  char* wdstL = (char*)Ws_lo + (w << 10);

  const f32x4 zero = {0.f, 0.f, 0.f, 0.f};
  f32x4 acc[4][4];
#pragma unroll
  for (int i = 0; i < 4; ++i)
#pragma unroll
    for (int j = 0; j < 4; ++j) acc[i][j] = zero;

  // fragment read addressing (swizzle depends only on fr since bases are mult-16)
  const int fr = lane & 15, qd = lane >> 4;
  const int qsw = ((qd ^ ((fr >> 1) & 3)) << 4);

  // prologue: A tile 0 into regs
  float4 a0 = *(const float4*)(Ap);
  float4 a1 = *(const float4*)(Ap + 4);

  float ss = 0.f;
  for (int kb = 0; kb < NKB; ++kb) {
    // ---- issue W tile loads (direct to LDS, pre-swizzled file) ----
    {
      const unsigned short* sh = wsrc0 + ((size_t)kb << 13);
      const unsigned short* sl = wsrc0l + ((size_t)kb << 13);
      gl_lds16(sh, wdstH);
      gl_lds16(sh + 4096, wdstH + 8192);
      gl_lds16(sl, wdstL);
      gl_lds16(sl + 4096, wdstL + 8192);
    }
    // ---- A: row sumsq + split -> swizzled LDS ----
    ss += a0.x * a0.x + a0.y * a0.y + a0.z * a0.z + a0.w * a0.w
        + a1.x * a1.x + a1.y * a1.y + a1.z * a1.z + a1.w * a1.w;
    {
      us8 h8, l8;
      float av[8] = {a0.x, a0.y, a0.z, a0.w, a1.x, a1.y, a1.z, a1.w};
#pragma unroll
      for (int j = 0; j < 8; ++j) {
        unsigned u = __float_as_uint(av[j]);
        float hif = __uint_as_float(u & 0xffff0000u);
        h8[j] = (unsigned short)(u >> 16);
        l8[j] = (unsigned short)((__float_as_uint(av[j] - hif) + 0x8000u) >> 16);
      }
      *(us8*)((char*)As_hi + awoff) = h8;
      *(us8*)((char*)As_lo + awoff) = l8;
    }
    __syncthreads();   // W in LDS (vmcnt drain), A writes visible

    // ---- prefetch next A tile into regs (drains at end barrier) ----
    const int kn = (kb + 1 < NKB) ? (kb + 1) << 5 : 0;
    float4 na0 = *(const float4*)(Ap + kn);
    float4 na1 = *(const float4*)(Ap + kn + 4);

    // ---- fragments + 3-product MFMA ----
    {
      bf16x8 ah[4], al[4], bh[4], bl[4];
#pragma unroll
      for (int mf = 0; mf < 4; ++mf) {
        const int off = ((wm << 6) + (mf << 4) + fr) * 64 + qsw;
        ah[mf] = *(const bf16x8*)((const char*)As_hi + off);
        al[mf] = *(const bf16x8*)((const char*)As_lo + off);
      }
#pragma unroll
      for (int nf = 0; nf < 4; ++nf) {
        const int off = ((wn << 6) + (nf << 4) + fr) * 64 + qsw;
        bh[nf] = *(const bf16x8*)((const char*)Ws_hi + off);
        bl[nf] = *(const bf16x8*)((const char*)Ws_lo + off);
      }
#pragma unroll
      for (int mf = 0; mf < 4; ++mf)
#pragma unroll
        for (int nf = 0; nf < 4; ++nf) {
          acc[mf][nf] = __builtin_amdgcn_mfma_f32_16x16x32_bf16(ah[mf], bh[nf], acc[mf][nf], 0, 0, 0);
          acc[mf][nf] = __builtin_amdgcn_mfma_f32_16x16x32_bf16(al[mf], bh[nf], acc[mf][nf], 0, 0, 0);
          acc[mf][nf] = __builtin_amdgcn_mfma_f32_16x16x32_bf16(ah[mf], bl[nf], acc[mf][nf], 0, 0, 0);
        }
    }
    __syncthreads();
    a0 = na0; a1 = na1;
  }

  // reduce the 4 staging partials per row (threads 4r..4r+3 are wave-adjacent)
  ss += __shfl_xor(ss, 1, 64);
  ss += __shfl_xor(ss, 2, 64);
  if ((t & 3) == 0) rn[ar] = ss;
  __syncthreads();
  if (t < 128) rn[t] = 1.0f / fmaxf(sqrtf(rn[t]), 1e-12f);
  __syncthreads();

  // C/D layout: col = lane&15, row = (lane>>4)*4 + reg  [m89-verified]
  const int er = lane & 15, eq = (lane >> 4) << 2;
#pragma unroll
  for (int mf = 0; mf < 4; ++mf) {
#pragma unroll
    for (int nf = 0; nf < 4; ++nf) {
#pragma unroll
      for (int r = 0; r < 4; ++r) {
        const int row = (wm << 6) + (mf << 4) + eq + r;
        const int col = (wn << 6) + (nf << 4) + er;
        g[(size_t)(row0 + row) * PDIM + col] = acc[mf][nf][r] * rn[row];
      }
    }
  }
}

// K3: 256 threads / 4 waves per block, 64 rows per block. (unchanged)
#define RB 64
#define CPAD 260
__global__ __launch_bounds__(256, 1) void k3_epilogue(const float* __restrict__ g,
                                                      const float* __restrict__ bvec,
                                                      const float* __restrict__ gamma,
                                                      const float* __restrict__ beta,
                                                      const float* __restrict__ C,
                                                      float* __restrict__ out,
                                                      int* __restrict__ cand,
                                                      int* __restrict__ list,
                                                      int* __restrict__ cnt,
                                                      double* __restrict__ partials) {
  __shared__ float Cs[KCB][CPAD];
  __shared__ float zsh[RB][CPAD];
  __shared__ float ccs[KCB];
  __shared__ float zzs[RB];
  __shared__ float lb[RB];
  __shared__ int idxsh[RB];
  const int t = threadIdx.x;
  const int lane = t & 63, w = t >> 6;
  const int row0 = blockIdx.x * RB;

  float4 creg[16];
#pragma unroll
  for (int i = 0; i < 16; ++i)
    creg[i] = *(const float4*)(C + (size_t)((t + (i << 8)) << 2));
#pragma unroll
  for (int i = 0; i < 16; ++i) {
    const int idx = t + (i << 8);
    *(float4*)&Cs[idx >> 6][(idx & 63) << 2] = creg[i];
  }
  __syncthreads();

  {
    const int kr = t >> 2, q = t & 3;
    float s = 0.f;
#pragma unroll
    for (int c = 0; c < 16; ++c) {
      float4 v = *(const float4*)&Cs[kr][(q << 6) + (c << 2)];
      s += v.x * v.x + v.y * v.y + v.z * v.z + v.w * v.w;
    }
    s += __shfl_xor(s, 1, 64);
    s += __shfl_xor(s, 2, 64);
    if (q == 0) ccs[kr] = s;
  }

  float4 bv = *(const float4*)(bvec + (lane << 2));
  float4 gm = *(const float4*)(gamma + (lane << 2));
  float4 bt = *(const float4*)(beta + (lane << 2));
  float4 gvv[16];
#pragma unroll
  for (int rr = 0; rr < 16; ++rr)
    gvv[rr] = *(const float4*)(g + (size_t)(row0 + (w << 4) + rr) * PDIM + (lane << 2));
#pragma unroll
  for (int rr = 0; rr < 16; ++rr) {
    const int r = (w << 4) + rr;
    float h0 = gvv[rr].x + bv.x, h1 = gvv[rr].y + bv.y;
    float h2 = gvv[rr].z + bv.z, h3 = gvv[rr].w + bv.w;
    float mu = wave_sum(h0 + h1 + h2 + h3) * (1.0f / 256.0f);
    float d0 = h0 - mu, d1 = h1 - mu, d2 = h2 - mu, d3 = h3 - mu;
    float var = wave_sum(d0 * d0 + d1 * d1 + d2 * d2 + d3 * d3) * (1.0f / 256.0f);
    float invs = 1.0f / sqrtf(var + 1e-5f);
    float zp0 = d0 * invs * gm.x + bt.x, zp1 = d1 * invs * gm.y + bt.y;
    float zp2 = d2 * invs * gm.z + bt.z, zp3 = d3 * invs * gm.w + bt.w;
    float nz = wave_sum(zp0 * zp0 + zp1 * zp1 + zp2 * zp2 + zp3 * zp3);
    float zn = 1.0f / fmaxf(sqrtf(nz), 1e-12f);
    float z0 = zp0 * zn, z1 = zp1 * zn, z2 = zp2 * zn, z3 = zp3 * zn;
    float zz = wave_sum(z0 * z0 + z1 * z1 + z2 * z2 + z3 * z3);
    float4 zf = {z0, z1, z2, z3};
    *(float4*)&zsh[r][lane << 2] = zf;
    if (lane == 0) zzs[r] = zz;
  }
  __syncthreads();

  const int kg = t & 15, rg = t >> 4;
  float p[4][4];
#pragma unroll
  for (int i = 0; i < 4; ++i)
#pragma unroll
    for (int j = 0; j < 4; ++j) p[i][j] = 0.f;

#pragma unroll 2
  for (int c4 = 0; c4 < 64; ++c4) {
    const int co = c4 << 2;
    float4 cv[4], zv[4];
#pragma unroll
    for (int ki = 0; ki < 4; ++ki) cv[ki] = *(const float4*)&Cs[kg + (ki << 4)][co];
#pragma unroll
    for (int ri = 0; ri < 4; ++ri) zv[ri] = *(const float4*)&zsh[rg + (ri << 4)][co];
#pragma unroll
    for (int ki = 0; ki < 4; ++ki)
#pragma unroll
      for (int ri = 0; ri < 4; ++ri) {
        p[ki][ri] = fmaf(cv[ki].x, zv[ri].x, p[ki][ri]);
        p[ki][ri] = fmaf(cv[ki].y, zv[ri].y, p[ki][ri]);
        p[ki][ri] = fmaf(cv[ki].z, zv[ri].z, p[ki][ri]);
        p[ki][ri] = fmaf(cv[ki].w, zv[ri].w, p[ki][ri]);
      }
  }

  float ccl[4];
#pragma unroll
  for (int ki = 0; ki < 4; ++ki) ccl[ki] = ccs[kg + (ki << 4)];

  float b1[4], b2[4];
  int i1[4];
#pragma unroll
  for (int ri = 0; ri < 4; ++ri) {
    const float zz = zzs[rg + (ri << 4)];
    b1[ri] = zz - 2.0f * p[0][ri] + ccl[0];
    i1[ri] = kg;
    b2[ri] = FLT_MAX;
#pragma unroll
    for (int ki = 1; ki < 4; ++ki) {
      const float d = zz - 2.0f * p[ki][ri] + ccl[ki];
      if (d < b1[ri]) { b2[ri] = b1[ri]; b1[ri] = d; i1[ri] = kg + (ki << 4); }
      else b2[ri] = fminf(b2[ri], d);
    }
  }
#pragma unroll
  for (int m = 1; m < 16; m <<= 1) {
#pragma unroll
    for (int ri = 0; ri < 4; ++ri) {
      float ob1 = __shfl_xor(b1[ri], m, 64);
      int oi1 = __shfl_xor(i1[ri], m, 64);
      float ob2 = __shfl_xor(b2[ri], m, 64);
      if (ob1 < b1[ri] || (ob1 == b1[ri] && oi1 < i1[ri])) {
        b2[ri] = fminf(b1[ri], ob2);
        b1[ri] = ob1; i1[ri] = oi1;
      } else {
        b2[ri] = fminf(b2[ri], ob1);
      }
    }
  }
  if (kg == 0) {
#pragma unroll
    for (int ri = 0; ri < 4; ++ri) {
      const int r = rg + (ri << 4);
      const int grow = row0 + r;
      cand[grow] = i1[ri];
      out[(size_t)NB * PDIM + grow] = (float)i1[ri];
      idxsh[r] = i1[ri];
      lb[r] = b1[ri];
      if (b2[ri] - b1[ri] < TAU) {
        int wpos = atomicAdd(cnt, 1);
        list[wpos] = grow;
      }
    }
  }
  __syncthreads();

#pragma unroll 4
  for (int rr = 0; rr < 16; ++rr) {
    const int r = (w << 4) + rr;
    const int ii = idxsh[r];
    float4 cv = *(const float4*)&Cs[ii][lane << 2];
    *(float4*)(out + (size_t)(row0 + r) * PDIM + (lane << 2)) = cv;
  }
  if (t == 0) {
    double s = 0.0;
    for (int r = 0; r < RB; ++r) s += (double)lb[r];
    partials[blockIdx.x] = s;
  }
}

// K4: fp64 recompute of flagged rows; fix index, output row, loss partial.
__global__ __launch_bounds__(256) void k4_refine(const float* __restrict__ A,
                                                 const float* __restrict__ W,
                                                 const float* __restrict__ bvec,
                                                 const float* __restrict__ gamma,
                                                 const float* __restrict__ beta,
                                                 const float* __restrict__ C,
                                                 const int* __restrict__ list,
                                                 const int* __restrict__ cnt,
                                                 int* __restrict__ cand,
                                                 float* __restrict__ out,
                                                 double* __restrict__ partials) {
  __shared__ double xs[DIN];
  __shared__ double red[256];
  __shared__ double zd[PDIM];
  __shared__ int idx2[2];
  const int t = threadIdx.x;
  const int n = *cnt;
  for (int it = blockIdx.x; it < n; it += gridDim.x) {
    const int row = list[it];
    __syncthreads();
    for (int i = t; i < DIN; i += 256) xs[i] = (double)A[(size_t)row * DIN + i];
    __syncthreads();
    double s = 0.0;
    for (int i = t; i < DIN; i += 256) s += xs[i] * xs[i];
    red[t] = s; __syncthreads();
    for (int m = 128; m; m >>= 1) { if (t < m) red[t] += red[t + m]; __syncthreads(); }
    const double inv = 1.0 / fmax(sqrt(red[0]), 1e-12);

    double gj = 0.0;
#pragma unroll 8
    for (int k = 0; k < DIN; ++k) gj += xs[k] * (double)W[(size_t)k * PDIM + t];
    const double h = gj * inv + (double)bvec[t];

    __syncthreads(); red[t] = h; __syncthreads();
    for (int m = 128; m; m >>= 1) { if (t < m) red[t] += red[t + m]; __syncthreads(); }
    const double mu = red[0] * (1.0 / 256.0);
    const double d = h - mu;
    __syncthreads(); red[t] = d * d; __syncthreads();
    for (int m = 128; m; m >>= 1) { if (t < m) red[t] += red[t + m]; __syncthreads(); }
    const double invs = 1.0 / sqrt(red[0] * (1.0 / 256.0) + 1e-5);
    const double zp = d * invs * (double)gamma[t] + (double)beta[t];
    __syncthreads(); red[t] = zp * zp; __syncthreads();
    for (int m = 128; m; m >>= 1) { if (t < m) red[t] += red[t + m]; __syncthreads(); }
    const double zn = 1.0 / fmax(sqrt(red[0]), 1e-12);
    const double z = zp * zn;
    zd[t] = z;
    __syncthreads(); red[t] = z * z; __syncthreads();
    for (int m = 128; m; m >>= 1) { if (t < m) red[t] += red[t + m]; __syncthreads(); }
    const double zz = red[0];
    __syncthreads();
    if (t < KCB) {
      double p = 0.0, cc = 0.0;
      for (int c = 0; c < PDIM; ++c) {
        double cv = (double)C[(size_t)t * PDIM + c];
        p += zd[c] * cv; cc += cv * cv;
      }
      red[t] = zz - 2.0 * p + cc;
    }
    __syncthreads();
    if (t == 0) {
      double best = red[0]; int bi = 0;
      for (int k = 1; k < KCB; ++k) if (red[k] < best) { best = red[k]; bi = k; }
      const int old = cand[row];
      idx2[0] = bi; idx2[1] = old;
      if (bi != old) {
        cand[row] = bi;
        out[(size_t)NB * PDIM + row] = (float)bi;
        atomicAdd(&partials[row >> 6], red[bi] - red[old]);
      }
    }
    __syncthreads();
    if (idx2[0] != idx2[1])
      out[(size_t)row * PDIM + t] = C[(size_t)idx2[0] * PDIM + t];
    __syncthreads();
  }
}

// K6: reduce loss partials, write scalar.
__global__ __launch_bounds__(256) void k6_finalize(const double* __restrict__ partials,
                                                   float* __restrict__ out) {
  __shared__ double red[256];
  const int t = threadIdx.x;
  double s = 0.0;
  for (int i = t; i < NB / RB; i += 256) s += partials[i];
  red[t] = s; __syncthreads();
  for (int m = 128; m; m >>= 1) { if (t < m) red[t] += red[t + m]; __syncthreads(); }
  if (t == 0)
    out[(size_t)NB * PDIM + NB] = (float)(0.25 * red[0] / ((double)NB * (double)PDIM));
}

extern "C" void kernel_launch(void* const* d_in, const int* in_sizes, int n_in,
                              void* d_out, int out_size, void* d_ws, size_t ws_size,
                              hipStream_t stream) {
  const float* z_frame  = (const float*)d_in[0];
  const float* W        = (const float*)d_in[1];
  const float* bvec     = (const float*)d_in[2];
  const float* gamma    = (const float*)d_in[3];
  const float* beta     = (const float*)d_in[4];
  const float* codebook = (const float*)d_in[5];
  float* out = (float*)d_out;

  char* ws = (char*)d_ws;
  int*    cnt      = (int*)(ws + OFF_CNT);
  int*    cand     = (int*)(ws + OFF_CAND);
  int*    list     = (int*)(ws + OFF_LIST);
  double* partials = (double*)(ws + OFF_PART);
  float*  g        = (float*)(ws + OFF_G);

  // WT scratch lives in the head of out (fully rewritten by K3/K4 later)
  unsigned short* WTh = (unsigned short*)out;
  unsigned short* WTl = WTh + WTL_OFS;

  hipMemsetAsync(ws + OFF_CNT, 0, 64, stream);

  k1_wconv<<<176, 256, 0, stream>>>(W, WTh, WTl);
  k2_gemm<<<NB / 128, 512, 0, stream>>>(z_frame, WTh, WTl, g);
  k3_epilogue<<<NB / RB, 256, 0, stream>>>(g, bvec, gamma, beta, codebook,
                                           out, cand, list, cnt, partials);
  k4_refine<<<256, 256, 0, stream>>>(z_frame, W, bvec, gamma, beta, codebook,
                                     list, cnt, cand, out, partials);
  k6_finalize<<<1, 256, 0, stream>>>(partials, out);
}